// Round 8
// baseline (226.385 us; speedup 1.0000x reference)
//
#include <hip/hip_runtime.h>
#include <stdint.h>

#define N_TOK  16384
#define EMB    512
#define NEMB   2048
#define NCHUNK 32            // 64 templates per chunk
#define CWIN   2.5e-4f       // ref-f32-grid + bf16 score-noise margin (passed R5-R7)

typedef __attribute__((ext_vector_type(8))) short s16x8;
typedef __attribute__((ext_vector_type(4))) float f32x4;

__device__ __forceinline__ unsigned short f2bf(float f) {   // RNE f32 -> bf16
  unsigned u = __float_as_uint(f);
  u += 0x7fffu + ((u >> 16) & 1u);
  return (unsigned short)(u >> 16);
}
// monotone f32 -> u32 (total order, NaN sorts above all reals)
__device__ __forceinline__ unsigned mapf(float f) {
  unsigned u = __float_as_uint(f);
  return (u >> 31) ? ~u : (u | 0x80000000u);
}
__device__ __forceinline__ float unmapf(unsigned u) {
  return __uint_as_float((u >> 31) ? (u & 0x7fffffffu) : ~u);
}

// DPP helpers: permute within 16-lane rows (all lanes active, bound_ctrl=1).
// quad_perm xor1 = 0xB1, xor2 = 0x4E; row_ror:4 = 0x124, row_ror:8 = 0x128.
template<int CTRL>
__device__ __forceinline__ float dppf(float x) {
  return __uint_as_float((unsigned)__builtin_amdgcn_update_dpp(
      0, (int)__float_as_uint(x), CTRL, 0xF, 0xF, true));
}
template<int CTRL>
__device__ __forceinline__ unsigned dppu(unsigned x) {
  return (unsigned)__builtin_amdgcn_update_dpp(0, (int)x, CTRL, 0xF, 0xF, true);
}

// numpy pairwise_sum emulation for sum(x*x) over 512 contiguous f32.
__device__ __forceinline__ float pairwise512_sq(const float* se, int lane) {
  int l = lane & 31;
  int b = l >> 3, j = l & 7;
  const float* base = se + b * 128 + j;
  float x = base[0];
  float r = __fmul_rn(x, x);
#pragma unroll
  for (int k = 1; k < 16; ++k) {
    float y = base[8 * k];
    r = __fadd_rn(r, __fmul_rn(y, y));
  }
  r = __fadd_rn(r, __shfl_xor(r, 1));
  r = __fadd_rn(r, __shfl_xor(r, 2));
  r = __fadd_rn(r, __shfl_xor(r, 4));
  r = __fadd_rn(r, __shfl_xor(r, 8));
  r = __fadd_rn(r, __shfl_xor(r, 16));
  return r;
}

// ---------- kernel 1: fused prep; bf16 copies stored PANEL-MAJOR ----------
// Panel-major: [rowblk = row/128][kt = col/32][128 rows][32 cols] bf16, i.e.
// each 8 KB K-panel contiguous -> score's global_load_lds streams densely.
__global__ __launch_bounds__(256) void prep_kernel(
    const float* __restrict__ tmp, const float* __restrict__ enc,
    unsigned short* __restrict__ thi, float* __restrict__ tsq,
    unsigned short* __restrict__ ehi, float* __restrict__ esq) {
  __shared__ float se[4][EMB];
  int wv = threadIdx.x >> 6, lane = threadIdx.x & 63;
  int row = blockIdx.x * 4 + wv;                             // 18432 rows
  bool isT = row < NEMB;
  const float* src = isT ? (tmp + (size_t)row * EMB)
                         : (enc + (size_t)(row - NEMB) * EMB);
  const float4* p = (const float4*)src + lane * 2;
  float4 v0 = p[0], v1 = p[1];
  float f[8] = {v0.x, v0.y, v0.z, v0.w, v1.x, v1.y, v1.z, v1.w};
  unsigned h[8];
#pragma unroll
  for (int i = 0; i < 8; ++i) { h[i] = f2bf(f[i]); se[wv][lane * 8 + i] = f[i]; }
  uint4 packed = { h[0] | (h[1] << 16), h[2] | (h[3] << 16),
                   h[4] | (h[5] << 16), h[6] | (h[7] << 16) };
  int lrow = isT ? row : row - NEMB;
  int blk = lrow >> 7, lr = lrow & 127;
  int kt = lane >> 2, cb = (lane & 3) * 16;
  char* base = (char*)(isT ? thi : ehi);
  *(uint4*)(base + (((size_t)(blk * 16 + kt)) << 13) + lr * 64 + cb) = packed;
  __syncthreads();
  float s = pairwise512_sq(se[wv], lane);
  if (lane == 0) { if (isT) tsq[row] = s; else esq[row - NEMB] = s; }
}

// ---------- kernel 2: 128x256-tile, 4-wave, 3-deep counted-vmcnt GEMM ----------
// K-loop + DPP epilogue frozen from R7 (43 us; 0 conflicts, no spill).
// ONLY change: keyc/s2c are now TOKEN-MAJOR ([token][chunk]) so the fused
// finish kernel reads each token's 32 keys as one 256-B contiguous block.
// Epilogue write becomes a few scalar stores from the 4 r==0 lanes/wave
// (byte volume unchanged). Scores BIT-IDENTICAL to R0..R7.
__global__ __launch_bounds__(256, 2) void score_kernel(
    const unsigned short* __restrict__ ehi, const unsigned short* __restrict__ thi,
    const float* __restrict__ tsq,
    unsigned long long* __restrict__ keyc, unsigned* __restrict__ s2c) {
  __shared__ __align__(16) char smem[73728];       // A: 3x8 KB, B at 24576: 3x16 KB
  const int tid = threadIdx.x, w = tid >> 6, lane = tid & 63;
  const int q = lane >> 4, r = lane & 15;
  const int wr = w >> 1, wc = w & 1;               // 2M x 2N wave grid
  const int tokb = (int)blockIdx.x >> 3;           // 0..127 (128 tokens each)
  const int nbp  = (int)blockIdx.x & 7;            // 0..7   (256 templates each)

  // ---- stage-source precompute (inverse swizzle of linear dest) ----
  const unsigned short* paA[2];
  const unsigned short* pbB[4];
#pragma unroll
  for (int i = 0; i < 2; ++i) {
    int Lp = i * 4096 + tid * 16;
    int P = Lp ^ (((Lp >> 7) & 3) << 4);
    paA[i] = (const unsigned short*)((const char*)ehi
             + (((size_t)tokb * 16) << 13) + (P >> 6) * 64 + (P & 63));
  }
#pragma unroll
  for (int i = 0; i < 4; ++i) {
    int Lp = i * 4096 + tid * 16;
    int P = Lp ^ (((Lp >> 7) & 3) << 4);
    int sub = P >> 13, rw = (P >> 6) & 127, cbyte = P & 63;
    pbB[i] = (const unsigned short*)((const char*)thi
             + (((size_t)((nbp * 2 + sub) * 16)) << 13) + rw * 64 + cbyte);
  }

#define GLD(src, dst)                                                    \
  __builtin_amdgcn_global_load_lds(                                      \
      (const __attribute__((address_space(1))) void*)(src),              \
      (__attribute__((address_space(3))) void*)(dst), 16, 0, 0)
#define STAGE(t) do {                                                    \
    char* da_ = smem + ((t) % 3) * 8192 + tid * 16;                      \
    char* db_ = smem + 24576 + ((t) % 3) * 16384 + tid * 16;             \
    GLD((const char*)paA[0] + (size_t)(t) * 8192, da_);                  \
    GLD((const char*)paA[1] + (size_t)(t) * 8192, da_ + 4096);           \
    GLD((const char*)pbB[0] + (size_t)(t) * 8192, db_);                  \
    GLD((const char*)pbB[1] + (size_t)(t) * 8192, db_ + 4096);           \
    GLD((const char*)pbB[2] + (size_t)(t) * 8192, db_ + 8192);           \
    GLD((const char*)pbB[3] + (size_t)(t) * 8192, db_ + 12288);          \
  } while (0)

  // ---- swizzled fragment-read offsets ----
  int offA[4], offB[8];
#pragma unroll
  for (int m = 0; m < 4; ++m) {
    int P = (wr * 64 + m * 16 + r) * 64 + q * 16;
    offA[m] = P ^ (((P >> 7) & 3) << 4);
  }
#pragma unroll
  for (int n = 0; n < 8; ++n) {
    int P = (wc * 128 + n * 16 + r) * 64 + q * 16;
    offB[n] = P ^ (((P >> 7) & 3) << 4);
  }

  f32x4 acc[4][8];
#pragma unroll
  for (int m = 0; m < 4; ++m)
#pragma unroll
    for (int n = 0; n < 8; ++n) acc[m][n] = (f32x4){0.f, 0.f, 0.f, 0.f};

  // ---- prologue: panels 0,1 in flight (12 units); need panel 0 -> vmcnt(6)
  STAGE(0); STAGE(1);
  asm volatile("s_waitcnt vmcnt(6)" ::: "memory");
  __builtin_amdgcn_s_barrier();

#pragma unroll
  for (int t = 0; t < 16; ++t) {
    const char* Ab_ = smem + (t % 3) * 8192;
    const char* Bb_ = smem + 24576 + (t % 3) * 16384;
    if (t + 2 < 16) STAGE(t + 2);                  // targets buf[(t-1)%3]: WAR-safe
    s16x8 af[4], bf[8];
#pragma unroll
    for (int m = 0; m < 4; ++m) af[m] = *(const s16x8*)(Ab_ + offA[m]);
#pragma unroll
    for (int n = 0; n < 8; ++n) bf[n] = *(const s16x8*)(Bb_ + offB[n]);
    __builtin_amdgcn_s_setprio(1);
#pragma unroll
    for (int n = 0; n < 8; ++n) {
      acc[0][n] = __builtin_amdgcn_mfma_f32_16x16x32_bf16(af[0], bf[n], acc[0][n], 0, 0, 0);
      acc[1][n] = __builtin_amdgcn_mfma_f32_16x16x32_bf16(af[1], bf[n], acc[1][n], 0, 0, 0);
      acc[2][n] = __builtin_amdgcn_mfma_f32_16x16x32_bf16(af[2], bf[n], acc[2][n], 0, 0, 0);
      acc[3][n] = __builtin_amdgcn_mfma_f32_16x16x32_bf16(af[3], bf[n], acc[3][n], 0, 0, 0);
    }
    __builtin_amdgcn_s_setprio(0);
    if (t < 14) { asm volatile("s_waitcnt vmcnt(6)" ::: "memory"); }
    else        { asm volatile("s_waitcnt vmcnt(0)" ::: "memory"); }
    __builtin_amdgcn_s_barrier();
  }

  // ---- epilogue: DPP float-pair argmin (R7-verified). Wave (wr,wc) owns
  // tokens tokb*128 + wr*64..+63 of chunks nbp*4 + wc*2 + {0,1}.
#define FOLD(CTRL) { float os_ = dppf<CTRL>(sb), os2_ = dppf<CTRL>(s2f);        \
    float mx_ = fmaxf(sb, os_);                                                 \
    s2f = fminf(fminf(s2f, os2_), mx_); sb = fminf(sb, os_); }
#define FOLDL(CTRL) { unsigned ol_ = dppu<CTRL>(li); li = li < ol_ ? li : ol_; }
#pragma unroll
  for (int nh = 0; nh < 2; ++nh) {
    const int chunk = nbp * 4 + wc * 2 + nh;
    const int nbase = chunk * 64;
    const float tq0 = tsq[nbase + r], tq1 = tsq[nbase + 16 + r],
                tq2 = tsq[nbase + 32 + r], tq3 = tsq[nbase + 48 + r];
#pragma unroll
    for (int m = 0; m < 4; ++m) {
      unsigned long long kk[4]; unsigned ss[4];
#pragma unroll
      for (int i = 0; i < 4; ++i) {
        float s0 = fmaf(-2.f, acc[m][nh * 4 + 0][i], tq0);  // == tq - fl(2*acc)
        float s1 = fmaf(-2.f, acc[m][nh * 4 + 1][i], tq1);
        float s2v = fmaf(-2.f, acc[m][nh * 4 + 2][i], tq2);
        float s3 = fmaf(-2.f, acc[m][nh * 4 + 3][i], tq3);
        // within-lane min + exact second-of-4 (dup-safe)
        float n01 = fminf(s0, s1), X01 = fmaxf(s0, s1);
        float n23 = fminf(s2v, s3), X23 = fmaxf(s2v, s3);
        float sb = fminf(n01, n23);
        float s2f = fminf(fminf(X01, X23), fmaxf(n01, n23));
        // row fold: (min, second) pair-merge, cyclic so all lanes get result
        FOLD(0xB1) FOLD(0x4E) FOLD(0x124) FOLD(0x128)
        // exact lexicographic index recovery: lowest (n,r) matching row-min
        unsigned li = 0xFFFFFFFFu;
        li = (s3  == sb) ? (unsigned)(48 + r) : li;
        li = (s2v == sb) ? (unsigned)(32 + r) : li;
        li = (s1  == sb) ? (unsigned)(16 + r) : li;
        li = (s0  == sb) ? (unsigned)(r)      : li;
        FOLDL(0xB1) FOLDL(0x4E) FOLDL(0x124) FOLDL(0x128)
        kk[i] = ((unsigned long long)mapf(sb) << 32) | (unsigned)(nbase + (int)li);
        ss[i] = mapf(s2f);
      }
      if (r == 0) {
        int token0 = tokb * 128 + wr * 64 + m * 16 + q * 4;
#pragma unroll
        for (int i = 0; i < 4; ++i) {
          keyc[(size_t)(token0 + i) * NCHUNK + chunk] = kk[i];
          s2c [(size_t)(token0 + i) * NCHUNK + chunk] = ss[i];
        }
      }
    }
  }
#undef FOLD
#undef FOLDL
#undef GLD
#undef STAGE
}

// ---------- kernel 3: fused finish = merge + inline rescan + gather ----------
// One wave per token. Lanes 0..31 load the token's 32 (key, s2) pairs
// (token-major: one 256-B contiguous block); 5-step butterfly with the exact
// associative (best, second) merge: combine((K1,S1),(K2,S2)) =
// (min(K1,K2), min(S1, S2, hi(max(K1,K2)))) — the loser's best enters
// second-tracking, matching the old sequential merge incl. duplicate-best.
// Margin-fail tokens rescan candidate chunks inline with the IDENTICAL f64
// summation (same j/k order, same 16-lane groups) as the old refine kernel ->
// bit-identical d2 keys; min over candidates is order-independent -> same idx.
// Output row + zidx written directly (old gather). Removes work/wcount/flag/
// bestIdx/rkey buffers, atomics, and 2 kernel launches.
__global__ __launch_bounds__(256) void finish_kernel(
    const float* __restrict__ enc, const float* __restrict__ tmp,
    const float* __restrict__ esq, const float* __restrict__ tsq,
    const unsigned long long* __restrict__ keyc, const unsigned* __restrict__ s2c,
    float* __restrict__ out) {
  __shared__ float se[4][EMB];
  const int wv = threadIdx.x >> 6, lane = threadIdx.x & 63;
  const int g = lane >> 4, l16 = lane & 15;
  const int t = blockIdx.x * 4 + wv;
  unsigned long long myk = ~0ULL; unsigned mys = 0xffffffffu;
  if (lane < 32) {
    myk = keyc[(size_t)t * NCHUNK + lane];
    mys = s2c[(size_t)t * NCHUNK + lane];
  }
  unsigned long long K = myk; unsigned S = mys;
#pragma unroll
  for (int mask = 1; mask < 32; mask <<= 1) {
    unsigned long long ko = __shfl_xor(K, mask);
    unsigned so = __shfl_xor(S, mask);
    unsigned long long mx = K > ko ? K : ko;
    unsigned hi = (unsigned)(mx >> 32);
    K = K < ko ? K : ko;
    S = S < so ? S : so;
    S = hi < S ? hi : S;
  }
  K = __shfl(K, 0); S = __shfl(S, 0);              // broadcast (lanes 32-63 too)
  float best_f   = unmapf((unsigned)(K >> 32));
  float second_f = unmapf(S);
  int idx = (int)(unsigned)(K & 0xffffffffu);
  bool ok = (second_f - best_f >= CWIN) && (idx >= 0) && (idx < NEMB) && (best_f == best_f);
  if (!ok) {
    const float4* erow = (const float4*)(enc + (size_t)t * EMB);
    ((float4*)se[wv])[lane]      = erow[lane];
    ((float4*)se[wv])[lane + 64] = erow[lane + 64];
    float e2 = esq[t];
    bool nanCase = !(best_f == best_f);
    float limit = best_f + CWIN;
    unsigned long long lkey = ~0ULL;
    for (int c = 0; c < NCHUNK; ++c) {
      float cf = unmapf((unsigned)(__shfl(myk, c) >> 32));
      if (nanCase || !(cf > limit)) {               // NaN-safe candidate test
#pragma unroll
        for (int j = 0; j < 16; ++j) {
          int m = c * 64 + j * 4 + g;
          const float4* trow = (const float4*)(tmp + (size_t)m * EMB);
          double s = 0.0;
#pragma unroll
          for (int k = 0; k < 8; ++k) {
            float4 a = trow[l16 + 16 * k];
            float4 b = ((const float4*)se[wv])[l16 + 16 * k];
            s += (double)a.x * b.x + (double)a.y * b.y
               + (double)a.z * b.z + (double)a.w * b.w;
          }
          s += __shfl_xor(s, 1); s += __shfl_xor(s, 2);
          s += __shfl_xor(s, 4); s += __shfl_xor(s, 8);
          if (l16 == 0) {
            float M  = (float)s;
            float d1 = __fadd_rn(e2, -__fmul_rn(2.0f, M));
            float d2 = __fadd_rn(d1, tsq[m]);        // full dist >= 0: bits monotone
            unsigned long long key =
                ((unsigned long long)__float_as_uint(d2) << 32) | (unsigned)m;
            if (key < lkey) lkey = key;
          }
        }
      }
    }
    { unsigned long long o = __shfl_xor(lkey, 16); lkey = lkey < o ? lkey : o; }
    { unsigned long long o = __shfl_xor(lkey, 32); lkey = lkey < o ? lkey : o; }
    idx = (int)(unsigned)(lkey & 0xffffffffULL);
  }
  idx = idx < 0 ? 0 : (idx > NEMB - 1 ? NEMB - 1 : idx);
  const float4* src = (const float4*)(tmp + (size_t)idx * EMB) + lane * 2;
  float4* dst = (float4*)(out + (size_t)t * EMB) + lane * 2;
  dst[0] = src[0];
  dst[1] = src[1];
  if (lane == 0) out[(size_t)N_TOK * EMB + t] = (float)idx;
}

extern "C" void kernel_launch(void* const* d_in, const int* in_sizes, int n_in,
                              void* d_out, int out_size, void* d_ws, size_t ws_size,
                              hipStream_t stream) {
  const float* enc = (const float*)d_in[0];
  const float* tmp = (const float*)d_in[1];
  float* out = (float*)d_out;
  char* ws = (char*)d_ws;
  unsigned short* thi = (unsigned short*)ws;                 //  2,097,152 B (panel-major)
  unsigned short* ehi = (unsigned short*)(ws + 2097152);     // 16,777,216 B (panel-major)
  float* tsq      = (float*)(ws + 18874368);                 //      8,192 B
  float* esq      = (float*)(ws + 18882560);                 //     65,536 B
  unsigned long long* keyc = (unsigned long long*)(ws + 18948096); // 4,194,304 B (token-major)
  unsigned* s2c   = (unsigned*)(ws + 23142400);              //  2,097,152 B (token-major)

  prep_kernel  <<<4608,     256, 0, stream>>>(tmp, enc, thi, tsq, ehi, esq);
  score_kernel <<<1024,     256, 0, stream>>>(ehi, thi, tsq, keyc, s2c);
  finish_kernel<<<N_TOK/4,  256, 0, stream>>>(enc, tmp, esq, tsq, keyc, s2c, out);
}

// Round 9
// 189.175 us; speedup vs baseline: 1.1967x; 1.1967x over previous
//
#include <hip/hip_runtime.h>
#include <stdint.h>

#define N_TOK  16384
#define EMB    512
#define NEMB   2048
#define NCHUNK 32            // 64 templates per chunk
#define CWIN   2.5e-4f       // ref-f32-grid + bf16 score-noise margin (passed R5-R7)

typedef __attribute__((ext_vector_type(8))) short s16x8;
typedef __attribute__((ext_vector_type(4))) float f32x4;

__device__ __forceinline__ unsigned short f2bf(float f) {   // RNE f32 -> bf16
  unsigned u = __float_as_uint(f);
  u += 0x7fffu + ((u >> 16) & 1u);
  return (unsigned short)(u >> 16);
}
// monotone f32 -> u32 (total order, NaN sorts above all reals)
__device__ __forceinline__ unsigned mapf(float f) {
  unsigned u = __float_as_uint(f);
  return (u >> 31) ? ~u : (u | 0x80000000u);
}
__device__ __forceinline__ float unmapf(unsigned u) {
  return __uint_as_float((u >> 31) ? (u & 0x7fffffffu) : ~u);
}

// DPP helpers: permute within 16-lane rows (all lanes active, bound_ctrl=1).
template<int CTRL>
__device__ __forceinline__ float dppf(float x) {
  return __uint_as_float((unsigned)__builtin_amdgcn_update_dpp(
      0, (int)__float_as_uint(x), CTRL, 0xF, 0xF, true));
}
template<int CTRL>
__device__ __forceinline__ unsigned dppu(unsigned x) {
  return (unsigned)__builtin_amdgcn_update_dpp(0, (int)x, CTRL, 0xF, 0xF, true);
}

// numpy pairwise_sum emulation for sum(x*x) over 512 contiguous f32.
__device__ __forceinline__ float pairwise512_sq(const float* se, int lane) {
  int l = lane & 31;
  int b = l >> 3, j = l & 7;
  const float* base = se + b * 128 + j;
  float x = base[0];
  float r = __fmul_rn(x, x);
#pragma unroll
  for (int k = 1; k < 16; ++k) {
    float y = base[8 * k];
    r = __fadd_rn(r, __fmul_rn(y, y));
  }
  r = __fadd_rn(r, __shfl_xor(r, 1));
  r = __fadd_rn(r, __shfl_xor(r, 2));
  r = __fadd_rn(r, __shfl_xor(r, 4));
  r = __fadd_rn(r, __shfl_xor(r, 8));
  r = __fadd_rn(r, __shfl_xor(r, 16));
  return r;
}

// ---------- kernel 1: fused prep; bf16 copies stored PANEL-MAJOR ----------
__global__ __launch_bounds__(256) void prep_kernel(
    const float* __restrict__ tmp, const float* __restrict__ enc,
    unsigned short* __restrict__ thi, float* __restrict__ tsq,
    unsigned short* __restrict__ ehi, float* __restrict__ esq,
    int* __restrict__ wcount) {
  __shared__ float se[4][EMB];
  int wv = threadIdx.x >> 6, lane = threadIdx.x & 63;
  int row = blockIdx.x * 4 + wv;                             // 18432 rows
  if (blockIdx.x == 0 && threadIdx.x == 0) *wcount = 0;
  bool isT = row < NEMB;
  const float* src = isT ? (tmp + (size_t)row * EMB)
                         : (enc + (size_t)(row - NEMB) * EMB);
  const float4* p = (const float4*)src + lane * 2;
  float4 v0 = p[0], v1 = p[1];
  float f[8] = {v0.x, v0.y, v0.z, v0.w, v1.x, v1.y, v1.z, v1.w};
  unsigned h[8];
#pragma unroll
  for (int i = 0; i < 8; ++i) { h[i] = f2bf(f[i]); se[wv][lane * 8 + i] = f[i]; }
  uint4 packed = { h[0] | (h[1] << 16), h[2] | (h[3] << 16),
                   h[4] | (h[5] << 16), h[6] | (h[7] << 16) };
  int lrow = isT ? row : row - NEMB;
  int blk = lrow >> 7, lr = lrow & 127;
  int kt = lane >> 2, cb = (lane & 3) * 16;
  char* base = (char*)(isT ? thi : ehi);
  *(uint4*)(base + (((size_t)(blk * 16 + kt)) << 13) + lr * 64 + cb) = packed;
  __syncthreads();
  float s = pairwise512_sq(se[wv], lane);
  if (lane == 0) { if (isT) tsq[row] = s; else esq[row - NEMB] = s; }
}

// ---------- kernel 2: 128x256-tile, 4-wave, 3-deep counted-vmcnt GEMM ----------
// FROZEN from R7/R8 (43 us; 0 conflicts, no spill). Token-major keyc/s2c.
// Scores BIT-IDENTICAL to R0..R8.
__global__ __launch_bounds__(256, 2) void score_kernel(
    const unsigned short* __restrict__ ehi, const unsigned short* __restrict__ thi,
    const float* __restrict__ tsq,
    unsigned long long* __restrict__ keyc, unsigned* __restrict__ s2c) {
  __shared__ __align__(16) char smem[73728];       // A: 3x8 KB, B at 24576: 3x16 KB
  const int tid = threadIdx.x, w = tid >> 6, lane = tid & 63;
  const int q = lane >> 4, r = lane & 15;
  const int wr = w >> 1, wc = w & 1;               // 2M x 2N wave grid
  const int tokb = (int)blockIdx.x >> 3;           // 0..127 (128 tokens each)
  const int nbp  = (int)blockIdx.x & 7;            // 0..7   (256 templates each)

  const unsigned short* paA[2];
  const unsigned short* pbB[4];
#pragma unroll
  for (int i = 0; i < 2; ++i) {
    int Lp = i * 4096 + tid * 16;
    int P = Lp ^ (((Lp >> 7) & 3) << 4);
    paA[i] = (const unsigned short*)((const char*)ehi
             + (((size_t)tokb * 16) << 13) + (P >> 6) * 64 + (P & 63));
  }
#pragma unroll
  for (int i = 0; i < 4; ++i) {
    int Lp = i * 4096 + tid * 16;
    int P = Lp ^ (((Lp >> 7) & 3) << 4);
    int sub = P >> 13, rw = (P >> 6) & 127, cbyte = P & 63;
    pbB[i] = (const unsigned short*)((const char*)thi
             + (((size_t)((nbp * 2 + sub) * 16)) << 13) + rw * 64 + cbyte);
  }

#define GLD(src, dst)                                                    \
  __builtin_amdgcn_global_load_lds(                                      \
      (const __attribute__((address_space(1))) void*)(src),              \
      (__attribute__((address_space(3))) void*)(dst), 16, 0, 0)
#define STAGE(t) do {                                                    \
    char* da_ = smem + ((t) % 3) * 8192 + tid * 16;                      \
    char* db_ = smem + 24576 + ((t) % 3) * 16384 + tid * 16;             \
    GLD((const char*)paA[0] + (size_t)(t) * 8192, da_);                  \
    GLD((const char*)paA[1] + (size_t)(t) * 8192, da_ + 4096);           \
    GLD((const char*)pbB[0] + (size_t)(t) * 8192, db_);                  \
    GLD((const char*)pbB[1] + (size_t)(t) * 8192, db_ + 4096);           \
    GLD((const char*)pbB[2] + (size_t)(t) * 8192, db_ + 8192);           \
    GLD((const char*)pbB[3] + (size_t)(t) * 8192, db_ + 12288);          \
  } while (0)

  int offA[4], offB[8];
#pragma unroll
  for (int m = 0; m < 4; ++m) {
    int P = (wr * 64 + m * 16 + r) * 64 + q * 16;
    offA[m] = P ^ (((P >> 7) & 3) << 4);
  }
#pragma unroll
  for (int n = 0; n < 8; ++n) {
    int P = (wc * 128 + n * 16 + r) * 64 + q * 16;
    offB[n] = P ^ (((P >> 7) & 3) << 4);
  }

  f32x4 acc[4][8];
#pragma unroll
  for (int m = 0; m < 4; ++m)
#pragma unroll
    for (int n = 0; n < 8; ++n) acc[m][n] = (f32x4){0.f, 0.f, 0.f, 0.f};

  STAGE(0); STAGE(1);
  asm volatile("s_waitcnt vmcnt(6)" ::: "memory");
  __builtin_amdgcn_s_barrier();

#pragma unroll
  for (int t = 0; t < 16; ++t) {
    const char* Ab_ = smem + (t % 3) * 8192;
    const char* Bb_ = smem + 24576 + (t % 3) * 16384;
    if (t + 2 < 16) STAGE(t + 2);                  // targets buf[(t-1)%3]: WAR-safe
    s16x8 af[4], bf[8];
#pragma unroll
    for (int m = 0; m < 4; ++m) af[m] = *(const s16x8*)(Ab_ + offA[m]);
#pragma unroll
    for (int n = 0; n < 8; ++n) bf[n] = *(const s16x8*)(Bb_ + offB[n]);
    __builtin_amdgcn_s_setprio(1);
#pragma unroll
    for (int n = 0; n < 8; ++n) {
      acc[0][n] = __builtin_amdgcn_mfma_f32_16x16x32_bf16(af[0], bf[n], acc[0][n], 0, 0, 0);
      acc[1][n] = __builtin_amdgcn_mfma_f32_16x16x32_bf16(af[1], bf[n], acc[1][n], 0, 0, 0);
      acc[2][n] = __builtin_amdgcn_mfma_f32_16x16x32_bf16(af[2], bf[n], acc[2][n], 0, 0, 0);
      acc[3][n] = __builtin_amdgcn_mfma_f32_16x16x32_bf16(af[3], bf[n], acc[3][n], 0, 0, 0);
    }
    __builtin_amdgcn_s_setprio(0);
    if (t < 14) { asm volatile("s_waitcnt vmcnt(6)" ::: "memory"); }
    else        { asm volatile("s_waitcnt vmcnt(0)" ::: "memory"); }
    __builtin_amdgcn_s_barrier();
  }

  // ---- epilogue: DPP float-pair argmin (R7-verified) ----
#define FOLD(CTRL) { float os_ = dppf<CTRL>(sb), os2_ = dppf<CTRL>(s2f);        \
    float mx_ = fmaxf(sb, os_);                                                 \
    s2f = fminf(fminf(s2f, os2_), mx_); sb = fminf(sb, os_); }
#define FOLDL(CTRL) { unsigned ol_ = dppu<CTRL>(li); li = li < ol_ ? li : ol_; }
#pragma unroll
  for (int nh = 0; nh < 2; ++nh) {
    const int chunk = nbp * 4 + wc * 2 + nh;
    const int nbase = chunk * 64;
    const float tq0 = tsq[nbase + r], tq1 = tsq[nbase + 16 + r],
                tq2 = tsq[nbase + 32 + r], tq3 = tsq[nbase + 48 + r];
#pragma unroll
    for (int m = 0; m < 4; ++m) {
      unsigned long long kk[4]; unsigned ss[4];
#pragma unroll
      for (int i = 0; i < 4; ++i) {
        float s0 = fmaf(-2.f, acc[m][nh * 4 + 0][i], tq0);  // == tq - fl(2*acc)
        float s1 = fmaf(-2.f, acc[m][nh * 4 + 1][i], tq1);
        float s2v = fmaf(-2.f, acc[m][nh * 4 + 2][i], tq2);
        float s3 = fmaf(-2.f, acc[m][nh * 4 + 3][i], tq3);
        float n01 = fminf(s0, s1), X01 = fmaxf(s0, s1);
        float n23 = fminf(s2v, s3), X23 = fmaxf(s2v, s3);
        float sb = fminf(n01, n23);
        float s2f = fminf(fminf(X01, X23), fmaxf(n01, n23));
        FOLD(0xB1) FOLD(0x4E) FOLD(0x124) FOLD(0x128)
        unsigned li = 0xFFFFFFFFu;
        li = (s3  == sb) ? (unsigned)(48 + r) : li;
        li = (s2v == sb) ? (unsigned)(32 + r) : li;
        li = (s1  == sb) ? (unsigned)(16 + r) : li;
        li = (s0  == sb) ? (unsigned)(r)      : li;
        FOLDL(0xB1) FOLDL(0x4E) FOLDL(0x124) FOLDL(0x128)
        kk[i] = ((unsigned long long)mapf(sb) << 32) | (unsigned)(nbase + (int)li);
        ss[i] = mapf(s2f);
      }
      if (r == 0) {
        int token0 = tokb * 128 + wr * 64 + m * 16 + q * 4;
#pragma unroll
        for (int i = 0; i < 4; ++i) {
          keyc[(size_t)(token0 + i) * NCHUNK + chunk] = kk[i];
          s2c [(size_t)(token0 + i) * NCHUNK + chunk] = ss[i];
        }
      }
    }
  }
#undef FOLD
#undef FOLDL
#undef GLD
#undef STAGE
}

// ---------- kernel 3: finish = merge + gather (uniform work only) ----------
// One wave per token. Lanes 0..31 load the token's 32 (key, s2) pairs; 5-step
// butterfly with the exact associative (best, second) merge (verified R8:
// ok-token rows exact). Passing tokens write their row + zidx here. Failing
// tokens post the token id to the worklist (lane 0, one atomicAdd) and write
// NOTHING — patch_kernel owns them. (R8's bug: fused rescan didn't broadcast
// lkey to all 64 lanes before the per-lane row gather; R8's perf bug: the
// variable-cost rescan serialized inside one wave. Both fixed by splitting.)
__global__ __launch_bounds__(256) void finish_kernel(
    const float* __restrict__ tmp,
    const unsigned long long* __restrict__ keyc, const unsigned* __restrict__ s2c,
    int* __restrict__ work, int* __restrict__ wcount,
    float* __restrict__ out) {
  const int wv = threadIdx.x >> 6, lane = threadIdx.x & 63;
  const int t = blockIdx.x * 4 + wv;
  unsigned long long K = ~0ULL; unsigned S = 0xffffffffu;
  if (lane < 32) {
    K = keyc[(size_t)t * NCHUNK + lane];
    S = s2c[(size_t)t * NCHUNK + lane];
  }
#pragma unroll
  for (int mask = 1; mask < 32; mask <<= 1) {
    unsigned long long ko = __shfl_xor(K, mask);
    unsigned so = __shfl_xor(S, mask);
    unsigned long long mx = K > ko ? K : ko;
    unsigned hi = (unsigned)(mx >> 32);
    K = K < ko ? K : ko;
    S = S < so ? S : so;
    S = hi < S ? hi : S;
  }
  K = __shfl(K, 0); S = __shfl(S, 0);              // broadcast to all 64 lanes
  float best_f   = unmapf((unsigned)(K >> 32));
  float second_f = unmapf(S);
  int idx = (int)(unsigned)(K & 0xffffffffu);
  bool ok = (second_f - best_f >= CWIN) && (idx >= 0) && (idx < NEMB) && (best_f == best_f);
  if (!ok) {
    if (lane == 0) { int pos = atomicAdd(wcount, 1); work[pos] = t; }
    return;                                        // patch_kernel writes this token
  }
  const float4* src = (const float4*)(tmp + (size_t)idx * EMB) + lane * 2;
  float4* dst = (float4*)(out + (size_t)t * EMB) + lane * 2;
  dst[0] = src[0];
  dst[1] = src[1];
  if (lane == 0) out[(size_t)N_TOK * EMB + t] = (float)idx;
}

// ---------- kernel 4: patch = f32-emulated rescan + row write, per token ----
// Block per worklist token (grid-stride). Candidate chunks re-derived from
// keyc exactly as the old merge (sequential best on thread 0 -> limit).
// Rescan is the old refine's proven shape: 256 threads cover 64 templates
// per chunk (m = c*64 + wv*16 + j*4 + g), IDENTICAL f64 summation order ->
// bit-identical d2 keys; min over candidates order-independent -> same idx.
// Block-reduce via shuffle folds + LDS with explicit broadcast; whole block
// then writes the row + zidx (single writer per failing token).
__global__ __launch_bounds__(256) void patch_kernel(
    const float* __restrict__ enc, const float* __restrict__ tmp,
    const float* __restrict__ esq, const float* __restrict__ tsq,
    const unsigned long long* __restrict__ keyc,
    const int* __restrict__ work, const int* __restrict__ wcount,
    float* __restrict__ out) {
  int total = *wcount;
  __shared__ float se[EMB];
  __shared__ float s_limit;
  __shared__ int s_nan;
  __shared__ unsigned long long s_min[4];
  __shared__ int s_idx;
  const int tid = threadIdx.x, wv = tid >> 6, lane = tid & 63;
  const int g = lane >> 4, l16 = lane & 15;
  for (int p = blockIdx.x; p < total; p += gridDim.x) {
    __syncthreads();                               // protect se/s_* reuse
    int t = work[p];
    const float4* erow = (const float4*)(enc + (size_t)t * EMB);
    for (int i = tid; i < 128; i += 256) ((float4*)se)[i] = erow[i];
    if (tid == 0) {
      unsigned long long K = ~0ULL;
      for (int c = 0; c < NCHUNK; ++c) {
        unsigned long long k = keyc[(size_t)t * NCHUNK + c];
        if (k < K) K = k;
      }
      float best_f = unmapf((unsigned)(K >> 32));
      s_limit = best_f + CWIN;
      s_nan = !(best_f == best_f) ? 1 : 0;
    }
    __syncthreads();
    float e2 = esq[t];
    float limit = s_limit;
    int nanCase = s_nan;
    unsigned long long lkey = ~0ULL;
    for (int c = 0; c < NCHUNK; ++c) {
      float cf = unmapf((unsigned)(keyc[(size_t)t * NCHUNK + c] >> 32));
      if (nanCase || !(cf > limit)) {               // NaN-safe candidate test
#pragma unroll
        for (int j = 0; j < 4; ++j) {
          int m = c * 64 + wv * 16 + j * 4 + g;
          const float4* trow = (const float4*)(tmp + (size_t)m * EMB);
          double s = 0.0;
#pragma unroll
          for (int k = 0; k < 8; ++k) {
            float4 a = trow[l16 + 16 * k];
            float4 b = ((const float4*)se)[l16 + 16 * k];
            s += (double)a.x * b.x + (double)a.y * b.y
               + (double)a.z * b.z + (double)a.w * b.w;
          }
          s += __shfl_xor(s, 1); s += __shfl_xor(s, 2);
          s += __shfl_xor(s, 4); s += __shfl_xor(s, 8);
          if (l16 == 0) {
            float M  = (float)s;
            float d1 = __fadd_rn(e2, -__fmul_rn(2.0f, M));
            float d2 = __fadd_rn(d1, tsq[m]);        // full dist >= 0: bits monotone
            unsigned long long key =
                ((unsigned long long)__float_as_uint(d2) << 32) | (unsigned)m;
            if (key < lkey) lkey = key;
          }
        }
      }
    }
    { unsigned long long o = __shfl_xor(lkey, 16); lkey = lkey < o ? lkey : o; }
    { unsigned long long o = __shfl_xor(lkey, 32); lkey = lkey < o ? lkey : o; }
    if (lane == 0) s_min[wv] = lkey;
    __syncthreads();
    if (tid == 0) {
      unsigned long long M = s_min[0];
      M = s_min[1] < M ? s_min[1] : M;
      M = s_min[2] < M ? s_min[2] : M;
      M = s_min[3] < M ? s_min[3] : M;
      int idx = (int)(unsigned)(M & 0xffffffffULL);
      s_idx = idx < 0 ? 0 : (idx > NEMB - 1 ? NEMB - 1 : idx);
    }
    __syncthreads();
    int idx = s_idx;
    const float4* srow = (const float4*)(tmp + (size_t)idx * EMB);
    float4* drow = (float4*)(out + (size_t)t * EMB);
    for (int i = tid; i < 128; i += 256) drow[i] = srow[i];
    if (tid == 0) out[(size_t)N_TOK * EMB + t] = (float)idx;
  }
}

extern "C" void kernel_launch(void* const* d_in, const int* in_sizes, int n_in,
                              void* d_out, int out_size, void* d_ws, size_t ws_size,
                              hipStream_t stream) {
  const float* enc = (const float*)d_in[0];
  const float* tmp = (const float*)d_in[1];
  float* out = (float*)d_out;
  char* ws = (char*)d_ws;
  unsigned short* thi = (unsigned short*)ws;                 //  2,097,152 B (panel-major)
  unsigned short* ehi = (unsigned short*)(ws + 2097152);     // 16,777,216 B (panel-major)
  float* tsq      = (float*)(ws + 18874368);                 //      8,192 B
  float* esq      = (float*)(ws + 18882560);                 //     65,536 B
  unsigned long long* keyc = (unsigned long long*)(ws + 18948096); // 4,194,304 B (token-major)
  unsigned* s2c   = (unsigned*)(ws + 23142400);              //  2,097,152 B (token-major)
  int*   wcount   = (int*)  (ws + 25239552);                 //         64 B
  int*   work     = (int*)  (ws + 25239616);                 //     65,536 B

  prep_kernel  <<<4608,     256, 0, stream>>>(tmp, enc, thi, tsq, ehi, esq, wcount);
  score_kernel <<<1024,     256, 0, stream>>>(ehi, thi, tsq, keyc, s2c);
  finish_kernel<<<N_TOK/4,  256, 0, stream>>>(tmp, keyc, s2c, work, wcount, out);
  patch_kernel <<<1024,     256, 0, stream>>>(enc, tmp, esq, tsq, keyc, work, wcount, out);
}

// Round 10
// 179.922 us; speedup vs baseline: 1.2582x; 1.0514x over previous
//
#include <hip/hip_runtime.h>
#include <stdint.h>

#define N_TOK  16384
#define EMB    512
#define NEMB   2048
#define NCHUNK 32            // 64 templates per chunk
#define CWIN   2.5e-4f       // ref-f32-grid + bf16 score-noise margin (passed R5-R7)

typedef __attribute__((ext_vector_type(8))) short s16x8;
typedef __attribute__((ext_vector_type(4))) float f32x4;

__device__ __forceinline__ unsigned short f2bf(float f) {   // RNE f32 -> bf16
  unsigned u = __float_as_uint(f);
  u += 0x7fffu + ((u >> 16) & 1u);
  return (unsigned short)(u >> 16);
}
// monotone f32 -> u32 (total order, NaN sorts above all reals)
__device__ __forceinline__ unsigned mapf(float f) {
  unsigned u = __float_as_uint(f);
  return (u >> 31) ? ~u : (u | 0x80000000u);
}
__device__ __forceinline__ float unmapf(unsigned u) {
  return __uint_as_float((u >> 31) ? (u & 0x7fffffffu) : ~u);
}

// DPP helpers: permute within 16-lane rows (all lanes active, bound_ctrl=1).
template<int CTRL>
__device__ __forceinline__ float dppf(float x) {
  return __uint_as_float((unsigned)__builtin_amdgcn_update_dpp(
      0, (int)__float_as_uint(x), CTRL, 0xF, 0xF, true));
}
template<int CTRL>
__device__ __forceinline__ unsigned dppu(unsigned x) {
  return (unsigned)__builtin_amdgcn_update_dpp(0, (int)x, CTRL, 0xF, 0xF, true);
}

// numpy pairwise_sum emulation for sum(x*x) over 512 contiguous f32.
__device__ __forceinline__ float pairwise512_sq(const float* se, int lane) {
  int l = lane & 31;
  int b = l >> 3, j = l & 7;
  const float* base = se + b * 128 + j;
  float x = base[0];
  float r = __fmul_rn(x, x);
#pragma unroll
  for (int k = 1; k < 16; ++k) {
    float y = base[8 * k];
    r = __fadd_rn(r, __fmul_rn(y, y));
  }
  r = __fadd_rn(r, __shfl_xor(r, 1));
  r = __fadd_rn(r, __shfl_xor(r, 2));
  r = __fadd_rn(r, __shfl_xor(r, 4));
  r = __fadd_rn(r, __shfl_xor(r, 8));
  r = __fadd_rn(r, __shfl_xor(r, 16));
  return r;
}

// ---------- kernel 1: fused prep; bf16 copies stored PANEL-MAJOR ----------
__global__ __launch_bounds__(256) void prep_kernel(
    const float* __restrict__ tmp, const float* __restrict__ enc,
    unsigned short* __restrict__ thi, float* __restrict__ tsq,
    unsigned short* __restrict__ ehi, float* __restrict__ esq,
    int* __restrict__ cnt) {
  __shared__ float se[4][EMB];
  int wv = threadIdx.x >> 6, lane = threadIdx.x & 63;
  int row = blockIdx.x * 4 + wv;                             // 18432 rows
  if (blockIdx.x == 0 && threadIdx.x == 0) { cnt[0] = 0; cnt[1] = 0; }
  bool isT = row < NEMB;
  const float* src = isT ? (tmp + (size_t)row * EMB)
                         : (enc + (size_t)(row - NEMB) * EMB);
  const float4* p = (const float4*)src + lane * 2;
  float4 v0 = p[0], v1 = p[1];
  float f[8] = {v0.x, v0.y, v0.z, v0.w, v1.x, v1.y, v1.z, v1.w};
  unsigned h[8];
#pragma unroll
  for (int i = 0; i < 8; ++i) { h[i] = f2bf(f[i]); se[wv][lane * 8 + i] = f[i]; }
  uint4 packed = { h[0] | (h[1] << 16), h[2] | (h[3] << 16),
                   h[4] | (h[5] << 16), h[6] | (h[7] << 16) };
  int lrow = isT ? row : row - NEMB;
  int blk = lrow >> 7, lr = lrow & 127;
  int kt = lane >> 2, cb = (lane & 3) * 16;
  char* base = (char*)(isT ? thi : ehi);
  *(uint4*)(base + (((size_t)(blk * 16 + kt)) << 13) + lr * 64 + cb) = packed;
  __syncthreads();
  float s = pairwise512_sq(se[wv], lane);
  if (lane == 0) { if (isT) tsq[row] = s; else esq[row - NEMB] = s; }
}

// ---------- kernel 2: 128x256-tile, 4-wave, 3-deep counted-vmcnt GEMM ----------
// FROZEN from R7/R8/R9 (43 us; 0 conflicts, no spill). Token-major keyc/s2c.
// Scores BIT-IDENTICAL to R0..R9.
__global__ __launch_bounds__(256, 2) void score_kernel(
    const unsigned short* __restrict__ ehi, const unsigned short* __restrict__ thi,
    const float* __restrict__ tsq,
    unsigned long long* __restrict__ keyc, unsigned* __restrict__ s2c) {
  __shared__ __align__(16) char smem[73728];       // A: 3x8 KB, B at 24576: 3x16 KB
  const int tid = threadIdx.x, w = tid >> 6, lane = tid & 63;
  const int q = lane >> 4, r = lane & 15;
  const int wr = w >> 1, wc = w & 1;               // 2M x 2N wave grid
  const int tokb = (int)blockIdx.x >> 3;           // 0..127 (128 tokens each)
  const int nbp  = (int)blockIdx.x & 7;            // 0..7   (256 templates each)

  const unsigned short* paA[2];
  const unsigned short* pbB[4];
#pragma unroll
  for (int i = 0; i < 2; ++i) {
    int Lp = i * 4096 + tid * 16;
    int P = Lp ^ (((Lp >> 7) & 3) << 4);
    paA[i] = (const unsigned short*)((const char*)ehi
             + (((size_t)tokb * 16) << 13) + (P >> 6) * 64 + (P & 63));
  }
#pragma unroll
  for (int i = 0; i < 4; ++i) {
    int Lp = i * 4096 + tid * 16;
    int P = Lp ^ (((Lp >> 7) & 3) << 4);
    int sub = P >> 13, rw = (P >> 6) & 127, cbyte = P & 63;
    pbB[i] = (const unsigned short*)((const char*)thi
             + (((size_t)((nbp * 2 + sub) * 16)) << 13) + rw * 64 + cbyte);
  }

#define GLD(src, dst)                                                    \
  __builtin_amdgcn_global_load_lds(                                      \
      (const __attribute__((address_space(1))) void*)(src),              \
      (__attribute__((address_space(3))) void*)(dst), 16, 0, 0)
#define STAGE(t) do {                                                    \
    char* da_ = smem + ((t) % 3) * 8192 + tid * 16;                      \
    char* db_ = smem + 24576 + ((t) % 3) * 16384 + tid * 16;             \
    GLD((const char*)paA[0] + (size_t)(t) * 8192, da_);                  \
    GLD((const char*)paA[1] + (size_t)(t) * 8192, da_ + 4096);           \
    GLD((const char*)pbB[0] + (size_t)(t) * 8192, db_);                  \
    GLD((const char*)pbB[1] + (size_t)(t) * 8192, db_ + 4096);           \
    GLD((const char*)pbB[2] + (size_t)(t) * 8192, db_ + 8192);           \
    GLD((const char*)pbB[3] + (size_t)(t) * 8192, db_ + 12288);          \
  } while (0)

  int offA[4], offB[8];
#pragma unroll
  for (int m = 0; m < 4; ++m) {
    int P = (wr * 64 + m * 16 + r) * 64 + q * 16;
    offA[m] = P ^ (((P >> 7) & 3) << 4);
  }
#pragma unroll
  for (int n = 0; n < 8; ++n) {
    int P = (wc * 128 + n * 16 + r) * 64 + q * 16;
    offB[n] = P ^ (((P >> 7) & 3) << 4);
  }

  f32x4 acc[4][8];
#pragma unroll
  for (int m = 0; m < 4; ++m)
#pragma unroll
    for (int n = 0; n < 8; ++n) acc[m][n] = (f32x4){0.f, 0.f, 0.f, 0.f};

  STAGE(0); STAGE(1);
  asm volatile("s_waitcnt vmcnt(6)" ::: "memory");
  __builtin_amdgcn_s_barrier();

#pragma unroll
  for (int t = 0; t < 16; ++t) {
    const char* Ab_ = smem + (t % 3) * 8192;
    const char* Bb_ = smem + 24576 + (t % 3) * 16384;
    if (t + 2 < 16) STAGE(t + 2);                  // targets buf[(t-1)%3]: WAR-safe
    s16x8 af[4], bf[8];
#pragma unroll
    for (int m = 0; m < 4; ++m) af[m] = *(const s16x8*)(Ab_ + offA[m]);
#pragma unroll
    for (int n = 0; n < 8; ++n) bf[n] = *(const s16x8*)(Bb_ + offB[n]);
    __builtin_amdgcn_s_setprio(1);
#pragma unroll
    for (int n = 0; n < 8; ++n) {
      acc[0][n] = __builtin_amdgcn_mfma_f32_16x16x32_bf16(af[0], bf[n], acc[0][n], 0, 0, 0);
      acc[1][n] = __builtin_amdgcn_mfma_f32_16x16x32_bf16(af[1], bf[n], acc[1][n], 0, 0, 0);
      acc[2][n] = __builtin_amdgcn_mfma_f32_16x16x32_bf16(af[2], bf[n], acc[2][n], 0, 0, 0);
      acc[3][n] = __builtin_amdgcn_mfma_f32_16x16x32_bf16(af[3], bf[n], acc[3][n], 0, 0, 0);
    }
    __builtin_amdgcn_s_setprio(0);
    if (t < 14) { asm volatile("s_waitcnt vmcnt(6)" ::: "memory"); }
    else        { asm volatile("s_waitcnt vmcnt(0)" ::: "memory"); }
    __builtin_amdgcn_s_barrier();
  }

  // ---- epilogue: DPP float-pair argmin (R7-verified) ----
#define FOLD(CTRL) { float os_ = dppf<CTRL>(sb), os2_ = dppf<CTRL>(s2f);        \
    float mx_ = fmaxf(sb, os_);                                                 \
    s2f = fminf(fminf(s2f, os2_), mx_); sb = fminf(sb, os_); }
#define FOLDL(CTRL) { unsigned ol_ = dppu<CTRL>(li); li = li < ol_ ? li : ol_; }
#pragma unroll
  for (int nh = 0; nh < 2; ++nh) {
    const int chunk = nbp * 4 + wc * 2 + nh;
    const int nbase = chunk * 64;
    const float tq0 = tsq[nbase + r], tq1 = tsq[nbase + 16 + r],
                tq2 = tsq[nbase + 32 + r], tq3 = tsq[nbase + 48 + r];
#pragma unroll
    for (int m = 0; m < 4; ++m) {
      unsigned long long kk[4]; unsigned ss[4];
#pragma unroll
      for (int i = 0; i < 4; ++i) {
        float s0 = fmaf(-2.f, acc[m][nh * 4 + 0][i], tq0);  // == tq - fl(2*acc)
        float s1 = fmaf(-2.f, acc[m][nh * 4 + 1][i], tq1);
        float s2v = fmaf(-2.f, acc[m][nh * 4 + 2][i], tq2);
        float s3 = fmaf(-2.f, acc[m][nh * 4 + 3][i], tq3);
        float n01 = fminf(s0, s1), X01 = fmaxf(s0, s1);
        float n23 = fminf(s2v, s3), X23 = fmaxf(s2v, s3);
        float sb = fminf(n01, n23);
        float s2f = fminf(fminf(X01, X23), fmaxf(n01, n23));
        FOLD(0xB1) FOLD(0x4E) FOLD(0x124) FOLD(0x128)
        unsigned li = 0xFFFFFFFFu;
        li = (s3  == sb) ? (unsigned)(48 + r) : li;
        li = (s2v == sb) ? (unsigned)(32 + r) : li;
        li = (s1  == sb) ? (unsigned)(16 + r) : li;
        li = (s0  == sb) ? (unsigned)(r)      : li;
        FOLDL(0xB1) FOLDL(0x4E) FOLDL(0x124) FOLDL(0x128)
        kk[i] = ((unsigned long long)mapf(sb) << 32) | (unsigned)(nbase + (int)li);
        ss[i] = mapf(s2f);
      }
      if (r == 0) {
        int token0 = tokb * 128 + wr * 64 + m * 16 + q * 4;
#pragma unroll
        for (int i = 0; i < 4; ++i) {
          keyc[(size_t)(token0 + i) * NCHUNK + chunk] = kk[i];
          s2c [(size_t)(token0 + i) * NCHUNK + chunk] = ss[i];
        }
      }
    }
  }
#undef FOLD
#undef FOLDL
#undef GLD
#undef STAGE
}

// ---------- kernel 3: finish = merge + gather + ITEM emission ----------
// One wave per token; butterfly merge (R9-verified exact). Passing tokens
// write row + zidx. Failing tokens: each lane<32 holds its chunk's key ->
// candidate test (nanCase || !(cf > limit), identical to old merge loop) is
// evaluated in parallel; one ballot + one atomicAdd reserves slots; candidate
// lanes write items (t*32+c) at their mask-rank. Lane 0 inits rkey[t] and
// posts t to the failing-token list. Item-granularity restores R7-refine's
// load balance (R9's per-token patch serialized candidates -> 51 us tail).
__global__ __launch_bounds__(256) void finish_kernel(
    const float* __restrict__ tmp,
    const unsigned long long* __restrict__ keyc, const unsigned* __restrict__ s2c,
    int* __restrict__ work, int* __restrict__ ftok, int* __restrict__ cnt,
    unsigned long long* __restrict__ rkey, float* __restrict__ out) {
  const int wv = threadIdx.x >> 6, lane = threadIdx.x & 63;
  const int t = blockIdx.x * 4 + wv;
  unsigned long long myk = ~0ULL; unsigned mys = 0xffffffffu;
  if (lane < 32) {
    myk = keyc[(size_t)t * NCHUNK + lane];
    mys = s2c[(size_t)t * NCHUNK + lane];
  }
  unsigned long long K = myk; unsigned S = mys;
#pragma unroll
  for (int mask = 1; mask < 32; mask <<= 1) {
    unsigned long long ko = __shfl_xor(K, mask);
    unsigned so = __shfl_xor(S, mask);
    unsigned long long mx = K > ko ? K : ko;
    unsigned hi = (unsigned)(mx >> 32);
    K = K < ko ? K : ko;
    S = S < so ? S : so;
    S = hi < S ? hi : S;
  }
  K = __shfl(K, 0); S = __shfl(S, 0);              // broadcast to all 64 lanes
  float best_f   = unmapf((unsigned)(K >> 32));
  float second_f = unmapf(S);
  int idx = (int)(unsigned)(K & 0xffffffffu);
  bool ok = (second_f - best_f >= CWIN) && (idx >= 0) && (idx < NEMB) && (best_f == best_f);
  if (!ok) {
    bool nanCase = !(best_f == best_f);
    float limit = best_f + CWIN;
    bool cand = false;
    if (lane < 32) {
      float cf = unmapf((unsigned)(myk >> 32));
      cand = nanCase || !(cf > limit);              // NaN-safe candidate test
    }
    unsigned long long mask = __ballot(cand);
    int base = 0;
    if (lane == 0) base = atomicAdd(&cnt[0], __popcll(mask));
    base = __shfl(base, 0);
    if (cand) {
      int rank = __popcll(mask & ((1ULL << lane) - 1ULL));
      work[base + rank] = t * NCHUNK + lane;
    }
    if (lane == 0) {
      rkey[t] = ~0ULL;
      int fp = atomicAdd(&cnt[1], 1);
      ftok[fp] = t;
    }
    return;                                        // patch+fixup own this token
  }
  const float4* src = (const float4*)(tmp + (size_t)idx * EMB) + lane * 2;
  float4* dst = (float4*)(out + (size_t)t * EMB) + lane * 2;
  dst[0] = src[0];
  dst[1] = src[1];
  if (lane == 0) out[(size_t)N_TOK * EMB + t] = (float)idx;
}

// ---------- kernel 4: patch = one (token,chunk) item per block ----------
// R7 refine's proven uniform shape: 256 threads cover the chunk's 64
// templates (m = c*64 + wv*16 + j*4 + g), IDENTICAL f64 summation order ->
// bit-identical d2 keys; block-min -> one atomicMin(rkey[t]) per item.
__global__ __launch_bounds__(256) void patch_kernel(
    const float* __restrict__ enc, const float* __restrict__ tmp,
    const float* __restrict__ esq, const float* __restrict__ tsq,
    const int* __restrict__ work, const int* __restrict__ cnt,
    unsigned long long* __restrict__ rkey) {
  int total = cnt[0];
  __shared__ float se[EMB];
  __shared__ unsigned long long s_min[4];
  const int tid = threadIdx.x, wv = tid >> 6, lane = tid & 63;
  const int g = lane >> 4, l16 = lane & 15;
  for (int p = blockIdx.x; p < total; p += gridDim.x) {
    __syncthreads();                               // protect se/s_min reuse
    int item = work[p];
    int t = item >> 5, c = item & 31;
    const float4* erow = (const float4*)(enc + (size_t)t * EMB);
    for (int i = tid; i < 128; i += 256) ((float4*)se)[i] = erow[i];
    __syncthreads();
    float e2 = esq[t];
    unsigned long long lkey = ~0ULL;
#pragma unroll
    for (int j = 0; j < 4; ++j) {
      int m = c * 64 + wv * 16 + j * 4 + g;
      const float4* trow = (const float4*)(tmp + (size_t)m * EMB);
      double s = 0.0;
#pragma unroll
      for (int k = 0; k < 8; ++k) {
        float4 a = trow[l16 + 16 * k];
        float4 b = ((const float4*)se)[l16 + 16 * k];
        s += (double)a.x * b.x + (double)a.y * b.y
           + (double)a.z * b.z + (double)a.w * b.w;
      }
      s += __shfl_xor(s, 1); s += __shfl_xor(s, 2);
      s += __shfl_xor(s, 4); s += __shfl_xor(s, 8);
      if (l16 == 0) {
        float M  = (float)s;
        float d1 = __fadd_rn(e2, -__fmul_rn(2.0f, M));
        float d2 = __fadd_rn(d1, tsq[m]);            // full dist >= 0: bits monotone
        unsigned long long key =
            ((unsigned long long)__float_as_uint(d2) << 32) | (unsigned)m;
        if (key < lkey) lkey = key;
      }
    }
    { unsigned long long o = __shfl_xor(lkey, 16); lkey = lkey < o ? lkey : o; }
    { unsigned long long o = __shfl_xor(lkey, 32); lkey = lkey < o ? lkey : o; }
    if (lane == 0) s_min[wv] = lkey;
    __syncthreads();
    if (tid == 0) {
      unsigned long long M = s_min[0];
      M = s_min[1] < M ? s_min[1] : M;
      M = s_min[2] < M ? s_min[2] : M;
      M = s_min[3] < M ? s_min[3] : M;
      atomicMin(&rkey[t], M);
    }
  }
}

// ---------- kernel 5: fixup = row write for failing tokens only ----------
__global__ __launch_bounds__(256) void fixup_kernel(
    const float* __restrict__ tmp, const int* __restrict__ ftok,
    const int* __restrict__ cnt, const unsigned long long* __restrict__ rkey,
    float* __restrict__ out) {
  int total = cnt[1];
  const int lane = threadIdx.x & 63;
  for (int widx = blockIdx.x * 4 + (threadIdx.x >> 6); widx < total;
       widx += gridDim.x * 4) {
    int t = ftok[widx];
    int idx = (int)(unsigned)(rkey[t] & 0xffffffffULL);
    idx = idx < 0 ? 0 : (idx > NEMB - 1 ? NEMB - 1 : idx);
    const float4* src = (const float4*)(tmp + (size_t)idx * EMB) + lane * 2;
    float4* dst = (float4*)(out + (size_t)t * EMB) + lane * 2;
    dst[0] = src[0];
    dst[1] = src[1];
    if (lane == 0) out[(size_t)N_TOK * EMB + t] = (float)idx;
  }
}

extern "C" void kernel_launch(void* const* d_in, const int* in_sizes, int n_in,
                              void* d_out, int out_size, void* d_ws, size_t ws_size,
                              hipStream_t stream) {
  const float* enc = (const float*)d_in[0];
  const float* tmp = (const float*)d_in[1];
  float* out = (float*)d_out;
  char* ws = (char*)d_ws;
  unsigned short* thi = (unsigned short*)ws;                 //  2,097,152 B (panel-major)
  unsigned short* ehi = (unsigned short*)(ws + 2097152);     // 16,777,216 B (panel-major)
  float* tsq      = (float*)(ws + 18874368);                 //      8,192 B
  float* esq      = (float*)(ws + 18882560);                 //     65,536 B
  unsigned long long* keyc = (unsigned long long*)(ws + 18948096); // 4,194,304 B (token-major)
  unsigned* s2c   = (unsigned*)(ws + 23142400);              //  2,097,152 B (token-major)
  int*   cnt      = (int*)  (ws + 25239552);                 //         64 B [items, ftokens]
  int*   ftok     = (int*)  (ws + 25239616);                 //     65,536 B
  unsigned long long* rkey = (unsigned long long*)(ws + 25305152); // 131,072 B
  int*   work     = (int*)  (ws + 25436224);                 //  2,097,152 B (items)

  prep_kernel  <<<4608,     256, 0, stream>>>(tmp, enc, thi, tsq, ehi, esq, cnt);
  score_kernel <<<1024,     256, 0, stream>>>(ehi, thi, tsq, keyc, s2c);
  finish_kernel<<<N_TOK/4,  256, 0, stream>>>(tmp, keyc, s2c, work, ftok, cnt, rkey, out);
  patch_kernel <<<2048,     256, 0, stream>>>(enc, tmp, esq, tsq, work, cnt, rkey);
  fixup_kernel <<<1024,     256, 0, stream>>>(tmp, ftok, cnt, rkey, out);
}